// Round 1
// 249.132 us; speedup vs baseline: 1.0024x; 1.0024x over previous
//
#include <hip/hip_runtime.h>
#include <math.h>
#include <stdint.h>

// Problem constants: B=2, S_DEC=2048, S_ENC=2048, D=1024, H=16, HD=64.
// Reference swaps args: Q <- enc_hidden, K/V <- dec_hidden.

typedef unsigned short ushort_t;
typedef __attribute__((ext_vector_type(8))) short short8;    // 8 x bf16 (4 VGPRs)
typedef __attribute__((ext_vector_type(4))) float floatx4;   // MFMA accumulator

__device__ __forceinline__ ushort_t f2bf(float x){
  unsigned u = __float_as_uint(x);
  u += 0x7fffu + ((u >> 16) & 1u);          // RNE
  return (ushort_t)(u >> 16);
}
__device__ __forceinline__ unsigned pk2bf(float a, float b){
#if __has_builtin(__builtin_amdgcn_cvt_pk_bf16_f32)
  typedef __attribute__((ext_vector_type(2))) __bf16 bf2_t;
  bf2_t r = __builtin_amdgcn_cvt_pk_bf16_f32(a, b);
  return *(unsigned*)&r;
#else
  return (unsigned)f2bf(a) | ((unsigned)f2bf(b) << 16);
#endif
}
__device__ __forceinline__ floatx4 mfma16(short8 a, short8 b, floatx4 c){
  return __builtin_amdgcn_mfma_f32_16x16x32_bf16(a, b, c, 0, 0, 0);
}

// ---------------- fused prep: conv + weight transposes + maskpack, one dispatch ----------------
// block ranges: [0,8192) conv enc/dec; [8192,8960) QKV weight transpose;
// [8960,9216) Wo transpose; [9216,41984) maskpack.
__global__ __launch_bounds__(256)
void prep_kernel(const float* __restrict__ enc, const float* __restrict__ dec,
                 const float* __restrict__ Wq, const float* __restrict__ Wk,
                 const float* __restrict__ Wv, const float* __restrict__ Wo,
                 const int* __restrict__ mask,
                 ushort_t* __restrict__ encb, ushort_t* __restrict__ decb,
                 ushort_t* __restrict__ WqT, ushort_t* __restrict__ WkT,
                 ushort_t* __restrict__ WvT, ushort_t* __restrict__ WoT,
                 unsigned long long* __restrict__ mb)
{
  __shared__ float t[64][65];
  const int bx = blockIdx.x, tid = threadIdx.x;
  if (bx < 8192){                      // fp32 -> bf16 casts
    const float* src = (bx < 4096) ? enc : dec;
    ushort_t*    dst = (bx < 4096) ? encb : decb;
    int i = ((bx & 4095) * 256 + tid) * 4;
    const float4 v = *(const float4*)(src + i);
    unsigned long long p = (unsigned long long)f2bf(v.x)
                         | ((unsigned long long)f2bf(v.y) << 16)
                         | ((unsigned long long)f2bf(v.z) << 32)
                         | ((unsigned long long)f2bf(v.w) << 48);
    *(unsigned long long*)(dst + i) = p;
  } else if (bx < 8960){               // QKV weight transpose: Wx[h][1024 d][64 k] -> WxT[(h*64+k)][1024 d]
    const int id = bx - 8192;          // 768 = 48 z * 16 y
    const int zz = id >> 4, yy = id & 15;
    const int which = zz >> 4, head = zz & 15;
    const float* src = (which == 0) ? Wq : (which == 1) ? Wk : Wv;
    ushort_t*    dst = (which == 0) ? WqT : (which == 1) ? WkT : WvT;
    const long sb = (long)head * 65536;
    const int r0 = yy * 64;
    #pragma unroll
    for (int i = 0; i < 16; i++){
      int idx = i*256 + tid;
      int r = idx >> 6, c = idx & 63;
      t[r][c] = src[sb + (long)(r0 + r)*64 + c];
    }
    __syncthreads();
    #pragma unroll
    for (int i = 0; i < 16; i++){
      int idx = i*256 + tid;
      int cr = idx >> 6, rc = idx & 63;
      dst[sb + (long)cr*1024 + r0 + rc] = f2bf(t[rc][cr]);
    }
  } else if (bx < 9216){               // Wo [1024 d][1024 e] -> WoT[e][d]
    const int id = bx - 8960;          // 256 = 16 x * 16 y
    const int r0 = (id >> 4) * 64, c0 = (id & 15) * 64;
    #pragma unroll
    for (int i = 0; i < 16; i++){
      int idx = i*256 + tid;
      int r = idx >> 6, c = idx & 63;
      t[r][c] = Wo[(long)(r0 + r)*1024 + c0 + c];
    }
    __syncthreads();
    #pragma unroll
    for (int i = 0; i < 16; i++){
      int idx = i*256 + tid;
      int cr = idx >> 6, rc = idx & 63;
      WoT[(long)(c0 + cr)*1024 + r0 + rc] = f2bf(t[rc][cr]);
    }
  } else {                             // mask -> bitmask (bit s of u64 word (b*2048+q)*32 + s/64)
    long gid = (long)(bx - 9216) * 256 + tid;
    unsigned long long bal = __ballot(mask[gid] != 0);
    if ((tid & 63) == 0) mb[gid >> 6] = bal;
  }
}

// ---------------- fused QKV projection GEMM (reg-staged dbuf, no vmcnt drain) ----------------
// grid (32 m, 8 n, 3). z=0: Q = (enc*WqT+bq)*Cscale; z=1: K = dec*WkT+bk (out [4096][1024],
// col = h*64+hd). z=2: remapped 8x16x2 computing V^T = WvT*dec^T + bv (out [bh][64][2048]).
// blockIdx.x = m-index -> XCD = bx%8 stripes M: per-XCD A-panel ~1 MB + weights 2 MB, L2-resident.
__global__ __launch_bounds__(256, 3)
void gemm_qkv_kernel(const ushort_t* __restrict__ encb, const ushort_t* __restrict__ decb,
                     const ushort_t* __restrict__ WqT, const ushort_t* __restrict__ WkT,
                     const ushort_t* __restrict__ WvT,
                     const float* __restrict__ bq, const float* __restrict__ bk,
                     const float* __restrict__ bv,
                     ushort_t* __restrict__ Qb, ushort_t* __restrict__ Kbf,
                     ushort_t* __restrict__ Vtb)
{
  __shared__ ushort_t At[2*4096];
  __shared__ ushort_t Bt[2*4096];
  const int tid = threadIdx.x;
  const int wave = tid >> 6, lane = tid & 63;
  const int quad = lane >> 4, l16 = lane & 15;
  const int z = blockIdx.z;
  const ushort_t *A, *BT; const float* bias; ushort_t* outp;
  int m0, n0; long outAdj = 0;
  float qs = 1.0f;
  if (z == 0){ A = encb; BT = WqT; bias = bq; outp = Qb;  m0 = blockIdx.x*128; n0 = blockIdx.y*128;
               qs = 0.18033688011112042f; }   // log2(e)/sqrt(64) folded into Q
  else if (z == 1){ A = decb; BT = WkT; bias = bk; outp = Kbf; m0 = blockIdx.x*128; n0 = blockIdx.y*128; }
  else {
    int id = blockIdx.x*8 + blockIdx.y;     // 0..255
    int vb = id >> 7, rem = id & 127;
    m0 = ((rem >> 4) & 7) * 128; n0 = (rem & 15) * 128;
    A = WvT; BT = decb + (long)vb*2097152; bias = bv; outp = Vtb; outAdj = (long)vb*2097152;
  }
  const int K = 1024;

  const int c0 = tid, c1 = 256 + tid;   // chunk -> row c>>2, col-chunk (c&3)*8 of [128][32] tile
  const ushort_t* gA0 = A  + (long)(m0 + (c0 >> 2))*K + (c0 & 3)*8;
  const ushort_t* gA1 = A  + (long)(m0 + (c1 >> 2))*K + (c1 & 3)*8;
  const ushort_t* gB0 = BT + (long)(n0 + (c0 >> 2))*K + (c0 & 3)*8;
  const ushort_t* gB1 = BT + (long)(n0 + (c1 >> 2))*K + (c1 & 3)*8;

  floatx4 acc[4][4];
  #pragma unroll
  for (int mt = 0; mt < 4; mt++)
    #pragma unroll
    for (int nt = 0; nt < 4; nt++)
      acc[mt][nt] = (floatx4){0.f, 0.f, 0.f, 0.f};

  // prologue: load tile 0 into regs
  short8 rA0 = *(const short8*)gA0;  gA0 += 32;
  short8 rA1 = *(const short8*)gA1;  gA1 += 32;
  short8 rB0 = *(const short8*)gB0;  gB0 += 32;
  short8 rB1 = *(const short8*)gB1;  gB1 += 32;

  const int moff = (wave & 1) * 64, noff = (wave >> 1) * 64;
  int cur = 0;
  for (int k0 = 0; k0 < K; k0 += 32){
    *(short8*)&At[cur*4096 +        tid*8] = rA0;
    *(short8*)&At[cur*4096 + 2048 + tid*8] = rA1;
    *(short8*)&Bt[cur*4096 +        tid*8] = rB0;
    *(short8*)&Bt[cur*4096 + 2048 + tid*8] = rB1;
    __syncthreads();                       // lgkmcnt only; global loads stay in flight
    if (k0 + 32 < K){
      rA0 = *(const short8*)gA0;  gA0 += 32;
      rA1 = *(const short8*)gA1;  gA1 += 32;
      rB0 = *(const short8*)gB0;  gB0 += 32;
      rB1 = *(const short8*)gB1;  gB1 += 32;
    }
    short8 af[4], bfr[4];
    #pragma unroll
    for (int t = 0; t < 4; t++){
      af[t]  = *(const short8*)&At[cur*4096 + (moff + t*16 + l16)*32 + quad*8];
      bfr[t] = *(const short8*)&Bt[cur*4096 + (noff + t*16 + l16)*32 + quad*8];
    }
    #pragma unroll
    for (int mt = 0; mt < 4; mt++)
      #pragma unroll
      for (int nt = 0; nt < 4; nt++)
        acc[mt][nt] = mfma16(bfr[nt], af[mt], acc[mt][nt]);   // C^T fragments
    cur ^= 1;
  }

  // epilogue: C^T frag -> lane holds act-row = l16, 4 consecutive channels (reg)
  #pragma unroll
  for (int mt = 0; mt < 4; mt++){
    #pragma unroll
    for (int nt = 0; nt < 4; nt++){
      floatx4 v = acc[mt][nt];
      if (z < 2){
        const int s   = m0 + moff + mt*16 + l16;
        const int ch0 = n0 + noff + nt*16 + quad*4;
        const float4 b4 = *(const float4*)&bias[ch0];
        uint2 pk;
        pk.x = pk2bf((v[0] + b4.x)*qs, (v[1] + b4.y)*qs);
        pk.y = pk2bf((v[2] + b4.z)*qs, (v[3] + b4.w)*qs);
        *(unsigned long long*)&outp[(long)s*1024 + ch0] = *(unsigned long long*)&pk;
      } else {
        const int ch = m0 + moff + mt*16 + l16;
        const int s0 = n0 + noff + nt*16 + quad*4;
        const float bb = bias[ch];
        uint2 pk;
        pk.x = pk2bf(v[0] + bb, v[1] + bb);
        pk.y = pk2bf(v[2] + bb, v[3] + bb);
        *(unsigned long long*)&outp[outAdj + (long)ch*2048 + s0] = *(unsigned long long*)&pk;
      }
    }
  }
}

// ---------------- output projection GEMM, 128x64 tiles, reg-staged dbuf ----------------
// grid (32 m, 16 n) = 512 blocks; XCD = bx%8 stripes M (A-panel L2-resident).
__global__ __launch_bounds__(256, 2)
void gemm_o_kernel(const ushort_t* __restrict__ A, const ushort_t* __restrict__ BT,
                   const float* __restrict__ bias, float* __restrict__ outf)
{
  __shared__ ushort_t At[2*4096];
  __shared__ ushort_t Bt[2*2048];
  const int tid = threadIdx.x;
  const int wave = tid >> 6, lane = tid & 63;
  const int quad = lane >> 4, l16 = lane & 15;
  const int m0 = blockIdx.x * 128, n0 = blockIdx.y * 64;
  const int K = 1024;

  const int c0 = tid, c1 = 256 + tid;
  const ushort_t* gA0 = A  + (long)(m0 + (c0 >> 2))*K + (c0 & 3)*8;
  const ushort_t* gA1 = A  + (long)(m0 + (c1 >> 2))*K + (c1 & 3)*8;
  const ushort_t* gB0 = BT + (long)(n0 + (c0 >> 2))*K + (c0 & 3)*8;   // 64 rows

  floatx4 acc[4][2];
  #pragma unroll
  for (int mt = 0; mt < 4; mt++)
    #pragma unroll
    for (int nt = 0; nt < 2; nt++)
      acc[mt][nt] = (floatx4){0.f, 0.f, 0.f, 0.f};

  short8 rA0 = *(const short8*)gA0;  gA0 += 32;
  short8 rA1 = *(const short8*)gA1;  gA1 += 32;
  short8 rB0 = *(const short8*)gB0;  gB0 += 32;

  const int moff = (wave & 1) * 64, noff = (wave >> 1) * 32;
  int cur = 0;
  for (int k0 = 0; k0 < K; k0 += 32){
    *(short8*)&At[cur*4096 +        tid*8] = rA0;
    *(short8*)&At[cur*4096 + 2048 + tid*8] = rA1;
    *(short8*)&Bt[cur*2048 +        tid*8] = rB0;
    __syncthreads();
    if (k0 + 32 < K){
      rA0 = *(const short8*)gA0;  gA0 += 32;
      rA1 = *(const short8*)gA1;  gA1 += 32;
      rB0 = *(const short8*)gB0;  gB0 += 32;
    }
    short8 af[4], bfr[2];
    #pragma unroll
    for (int t = 0; t < 4; t++)
      af[t]  = *(const short8*)&At[cur*4096 + (moff + t*16 + l16)*32 + quad*8];
    #pragma unroll
    for (int t = 0; t < 2; t++)
      bfr[t] = *(const short8*)&Bt[cur*2048 + (noff + t*16 + l16)*32 + quad*8];
    #pragma unroll
    for (int mt = 0; mt < 4; mt++)
      #pragma unroll
      for (int nt = 0; nt < 2; nt++)
        acc[mt][nt] = mfma16(bfr[nt], af[mt], acc[mt][nt]);   // C^T fragments
    cur ^= 1;
  }

  // epilogue: lane holds s = l16, 4 consecutive out channels -> float4 store
  #pragma unroll
  for (int mt = 0; mt < 4; mt++){
    #pragma unroll
    for (int nt = 0; nt < 2; nt++){
      const int s   = m0 + moff + mt*16 + l16;
      const int ch0 = n0 + noff + nt*16 + quad*4;
      const float4 b4 = *(const float4*)&bias[ch0];
      float4 o;
      o.x = acc[mt][nt][0] + b4.x;
      o.y = acc[mt][nt][1] + b4.y;
      o.z = acc[mt][nt][2] + b4.z;
      o.w = acc[mt][nt][3] + b4.w;
      *(float4*)&outf[(long)s*1024 + ch0] = o;
    }
  }
}

// ---------------- flash attention: full-rate K=32 PV via permuted K staging ----------------
// grid (32 bh, 16 qt); block 512 = 8 waves, each owning ONE 16-row q-subtile.
// (Occupancy fix: was 4 waves x 32 q rows -> 2 waves/SIMD, latency-bound at MfmaUtil 21% /
// VALUBusy 44% / Occ 18.6%. 8-wave blocks at same grid give 16 waves/CU = 4 waves/SIMD.)
// s-tile = 64 per round (2 chunks of 32), 32 rounds, reg->LDS double-buffered staging.
//
// Permutation trick: for chunk c, half h in {0,1}, the S^T MFMA's K-operand rows are staged
// so that C-frag row quad*4+r corresponds to s_local = c*32 + quad*8 + h*4 + r. Then the two
// C-frags (h=0,1) of one chunk hold exactly s = c*32 + quad*8 + {0..7} per lane — which IS the
// B-operand layout (k = quad*8+j) of a FULL-RATE 16x16x32 PV MFMA. V^T A-frag reads 8
// consecutive s per lane = one b128 from natural [hd][s] layout. O^T accumulates in C-layout
// (row=hd-local, col=q=l16). One-pass exp2 softmax (Q pre-scaled by log2(e)/8 in the GEMM);
// lsum per-lane (q=l16) -> no shuffle for inv.
__global__ __launch_bounds__(512, 4)
void flash_attn_kernel(const ushort_t* __restrict__ Qp, const ushort_t* __restrict__ Kp,
                       const ushort_t* __restrict__ Vt, const unsigned* __restrict__ mb,
                       ushort_t* __restrict__ aout)
{
  __shared__ ushort_t Kbuf[2*4608];   // [64 rows (permuted)][72] per buf
  __shared__ ushort_t Vbuf[2*4608];   // [64 hd][72] per buf (natural [hd][s_local])
  const int tid = threadIdx.x, wave = tid >> 6, lane = tid & 63;
  const int quad = lane >> 4, l16 = lane & 15;
  const int bh = blockIdx.x, qt = blockIdx.y;
  const int b = bh >> 4, h = bh & 15;

  const ushort_t* VB = Vt + (long)bh*131072;
  const int q0 = qt*128 + wave*16;

  // Q fragments (B operand of S^T: n=q=l16, k=hd), pre-scaled by log2(e)/8 in GEMM
  short8 qf0, qf1;
  {
    const long qrow = ((long)b*2048 + q0 + l16)*1024 + h*64;
    qf0 = *(const short8*)&Qp[qrow +      quad*8];
    qf1 = *(const short8*)&Qp[qrow + 32 + quad*8];
  }

  floatx4 accO[4];
  #pragma unroll
  for (int ht = 0; ht < 4; ht++) accO[ht] = (floatx4){0.f,0.f,0.f,0.f};
  float lsum = 0.f;

  // staging: 512 threads x 1 chunk x 16B each for K and V cover one 64x64 tile
  // (src row tid>>3, col (tid&7)*8).
  // K dest row permutation: s_local -> c*32 + h*16 + quadp*4 + r  where
  //   c = s>>5, t = s&31, quadp = t>>3, h = (t&7)>>2, r = t&3.
  const int sr = tid >> 3;
  const int kr = (sr & 32) + ((sr & 4) << 2) + ((sr >> 3) & 3)*4 + (sr & 3);
  const ushort_t* gK = Kp + ((long)b*2048 + sr)*1024 + h*64 + (tid & 7)*8;
  const ushort_t* gV = VB + (long)sr*2048 + (tid & 7)*8;
  const int ko = kr*72 + (tid & 7)*8;
  const int vo = sr*72 + (tid & 7)*8;

  const uint2* mb2 = (const uint2*)mb;
  const long mbase = (long)b*2048 + q0;

  // prefetch tile 0 into regs (K rows advance 64*1024 shorts/round; V cols advance 64)
  short8 gk = *(const short8*)gK;  gK += 65536;
  short8 gv = *(const short8*)gV;  gV += 64;

  int cur = 0;
  for (int st = 0; st < 32; st++){
    *(short8*)&Kbuf[cur*4608 + ko] = gk;
    *(short8*)&Vbuf[cur*4608 + vo] = gv;
    __syncthreads();                      // buf[cur] valid for all waves
    if (st < 31){                         // prefetch next tile (hidden under compute)
      gk = *(const short8*)gK;  gK += 65536;
      gv = *(const short8*)gV;  gV += 64;
    }
    const ushort_t* Kt = &Kbuf[cur*4608];
    const ushort_t* Vp = &Vbuf[cur*4608];

    // mask words (64 bits for this wave's q-subtile x s-tile)
    uint2 mw = mb2[(mbase + l16)*32 + st];
    const bool uni = __all((mw.x & mw.y) == 0xFFFFFFFFu);

    #pragma unroll
    for (int c = 0; c < 2; c++){
      // K fragments for both halves of this 32-s chunk
      short8 kA0 = *(const short8*)&Kt[((c*2    )*16 + l16)*72 +      quad*8];
      short8 kA1 = *(const short8*)&Kt[((c*2    )*16 + l16)*72 + 32 + quad*8];
      short8 kB0 = *(const short8*)&Kt[((c*2 + 1)*16 + l16)*72 +      quad*8];
      short8 kB1 = *(const short8*)&Kt[((c*2 + 1)*16 + l16)*72 + 32 + quad*8];
      // V^T A-frags: lane hd=l16(+16*ht), k = s_local = c*32 + quad*8 + 0..7 -> b128
      short8 vf[4];
      #pragma unroll
      for (int ht = 0; ht < 4; ht++)
        vf[ht] = *(const short8*)&Vp[(ht*16 + l16)*72 + c*32 + quad*8];

      floatx4 zA = (floatx4){0.f,0.f,0.f,0.f};
      zA = mfma16(kA0, qf0, zA);
      zA = mfma16(kA1, qf1, zA);
      floatx4 zB = (floatx4){0.f,0.f,0.f,0.f};
      zB = mfma16(kB0, qf0, zB);
      zB = mfma16(kB1, qf1, zB);
      // s_local = c*32 + quad*8 + (h*4 + r): h=0 -> zA, h=1 -> zB
      float pA0 = __builtin_amdgcn_exp2f(zA[0]);
      float pA1 = __builtin_amdgcn_exp2f(zA[1]);
      float pA2 = __builtin_amdgcn_exp2f(zA[2]);
      float pA3 = __builtin_amdgcn_exp2f(zA[3]);
      float pB0 = __builtin_amdgcn_exp2f(zB[0]);
      float pB1 = __builtin_amdgcn_exp2f(zB[1]);
      float pB2 = __builtin_amdgcn_exp2f(zB[2]);
      float pB3 = __builtin_amdgcn_exp2f(zB[3]);
      if (__builtin_expect(!uni, 0)){
        const unsigned w = c ? mw.y : mw.x;
        const int sh = quad*8;
        pA0 = ((w >> (sh+0)) & 1u) ? pA0 : 0.f;
        pA1 = ((w >> (sh+1)) & 1u) ? pA1 : 0.f;
        pA2 = ((w >> (sh+2)) & 1u) ? pA2 : 0.f;
        pA3 = ((w >> (sh+3)) & 1u) ? pA3 : 0.f;
        pB0 = ((w >> (sh+4)) & 1u) ? pB0 : 0.f;
        pB1 = ((w >> (sh+5)) & 1u) ? pB1 : 0.f;
        pB2 = ((w >> (sh+6)) & 1u) ? pB2 : 0.f;
        pB3 = ((w >> (sh+7)) & 1u) ? pB3 : 0.f;
      }
      lsum += ((pA0 + pA1) + (pA2 + pA3)) + ((pB0 + pB1) + (pB2 + pB3));
      unsigned pk[4];
      pk[0] = pk2bf(pA0, pA1);
      pk[1] = pk2bf(pA2, pA3);
      pk[2] = pk2bf(pB0, pB1);
      pk[3] = pk2bf(pB2, pB3);
      short8 pb;
      __builtin_memcpy(&pb, pk, 16);    // B-operand: k = quad*8 + j, j=0..7 = s_local order
      #pragma unroll
      for (int ht = 0; ht < 4; ht++)
        accO[ht] = mfma16(vf[ht], pb, accO[ht]);   // full-rate K=32 PV
    }
    cur ^= 1;
  }

  // lsum: quads hold disjoint s-partials of the same q=l16
  lsum += __shfl_xor(lsum, 16);
  lsum += __shfl_xor(lsum, 32);

  // O^T C-layout: lane holds q = l16, hd = ht*16 + quad*4 + reg -> u64 per ht
  {
    const float inv = 1.0f / lsum;
    const long rowo = ((long)b*2048 + q0 + l16)*1024 + h*64;
    #pragma unroll
    for (int ht = 0; ht < 4; ht++){
      uint2 pk;
      pk.x = pk2bf(accO[ht][0]*inv, accO[ht][1]*inv);
      pk.y = pk2bf(accO[ht][2]*inv, accO[ht][3]*inv);
      *(unsigned long long*)&aout[rowo + ht*16 + quad*4] = *(unsigned long long*)&pk;
    }
  }
}

extern "C" void kernel_launch(void* const* d_in, const int* in_sizes, int n_in,
                              void* d_out, int out_size, void* d_ws, size_t ws_size,
                              hipStream_t stream) {
  const float* dec  = (const float*)d_in[0];
  const float* enc  = (const float*)d_in[1];
  const int*   mask = (const int*)d_in[2];
  const float* Wq   = (const float*)d_in[3];
  const float* bq   = (const float*)d_in[4];
  const float* Wk   = (const float*)d_in[5];
  const float* bk   = (const float*)d_in[6];
  const float* Wv   = (const float*)d_in[7];
  const float* bv   = (const float*)d_in[8];
  const float* Wo   = (const float*)d_in[9];
  const float* bo   = (const float*)d_in[10];
  float* out = (float*)d_out;

  // workspace layout (bf16 = ushort). Total ~51.4 MB.
  ushort_t* ws   = (ushort_t*)d_ws;
  ushort_t* encb = ws;                    // [4096][1024]; reused as attn output after Q-proj
  ushort_t* decb = encb + 4194304;        // [4096][1024]
  ushort_t* Qb   = decb + 4194304;        // [4096][1024] plain (col = h*64+hd), pre-scaled
  ushort_t* Kbf  = Qb   + 4194304;        // [4096][1024] plain
  ushort_t* Vtb  = Kbf  + 4194304;        // [B*H][64][2048]
  ushort_t* WqT  = Vtb  + 4194304;        // [1024 c][1024 d]
  ushort_t* WkT  = WqT  + 1048576;
  ushort_t* WvT  = WkT  + 1048576;
  ushort_t* WoT  = WvT  + 1048576;
  unsigned* Mb   = (unsigned*)(WoT + 1048576);  // 262144 u32 = 1 MB bitmask

  // all prep in one dispatch (conv / weight transposes / maskpack)
  prep_kernel<<<41984, 256, 0, stream>>>(enc, dec, Wq, Wk, Wv, Wo, mask,
                                         encb, decb, WqT, WkT, WvT, WoT,
                                         (unsigned long long*)Mb);
  // Q, K, V projections in one dispatch (768 blocks = 3/CU; m stripes XCDs)
  gemm_qkv_kernel<<<dim3(32,8,3), 256, 0, stream>>>(encb, decb, WqT, WkT, WvT,
                                                    bq, bk, bv, Qb, Kbf, Vtb);
  // attention (writes attn bf16 into encb, free after Q-proj); 8-wave blocks for occupancy
  flash_attn_kernel<<<dim3(32,16,1), 512, 0, stream>>>(Qb, Kbf, Vtb, Mb, encb);
  // out = attn * Wo + bo (fp32), 128x64 tiles (m stripes XCDs)
  gemm_o_kernel<<<dim3(32,16,1), 256, 0, stream>>>(encb, WoT, bo, out);
}